// Round 7
// baseline (1344.231 us; speedup 1.0000x reference)
//
#include <hip/hip_runtime.h>

#define NNODES 100000
#define NEDGES 1600000
#define NGRAPHS 64
#define HID 128
#define OUTD 256
#define NLAYERS 5
#define BN_EPS 1e-5f
#define NBUCK 196          // ceil(NNODES/512)
#define BUCKCAP 9216       // avg 8192 edges/bucket + 11 sigma
#define FILL_BLOCKS 391    // ceil(NEDGES/4096)
#define NREP 8             // stats atomic replicas
#define ZSTR 136           // LDS z-tile row stride in ushorts (272B: 16B-aligned, bank-safe)

typedef __attribute__((ext_vector_type(8))) short short8;
typedef __attribute__((ext_vector_type(4))) float f32x4;

__device__ inline unsigned short f2b(float f) {
    union { float f; unsigned int u; } a; a.f = f;
    unsigned int u = a.u;
    return (unsigned short)((u + 0x7FFF + ((u >> 16) & 1)) >> 16);  // RNE
}
__device__ inline float b2f(unsigned short b) {
    union { unsigned int u; float f; } a; a.u = ((unsigned int)b) << 16;
    return a.f;
}

// ---------------- init: h = x (fp32) and hb = bf16(x) ----------------
__global__ void k_init(const float* __restrict__ x, float* __restrict__ h,
                       ushort* __restrict__ hb) {
    int i = blockIdx.x * 256 + threadIdx.x;  // float4 index
    float4 v = ((const float4*)x)[i];
    ((float4*)h)[i] = v;
    ushort4 o;
    o.x = f2b(v.x); o.y = f2b(v.y); o.z = f2b(v.z); o.w = f2b(v.w);
    ((ushort4*)hb)[i] = o;
}

// ---------------- CSR build (bucketed) ----------------
__global__ void k_bcur0(int* __restrict__ bcur) {
    int t = threadIdx.x;
    if (t < NBUCK) bcur[t] = t * BUCKCAP;
}

__global__ __launch_bounds__(256) void k_fill1(
    const int* __restrict__ srcv, const int* __restrict__ dstv,
    int* __restrict__ bcur, unsigned int* __restrict__ packed) {
    __shared__ int hist[NBUCK];
    __shared__ int base[NBUCK];
    int tid = threadIdx.x;
    int e0 = blockIdx.x * 4096;
    for (int i = tid; i < NBUCK; i += 256) hist[i] = 0;
    __syncthreads();
#pragma unroll
    for (int i = 0; i < 16; i++) {
        int e = e0 + i * 256 + tid;
        if (e < NEDGES) atomicAdd(&hist[dstv[e] >> 9], 1);
    }
    __syncthreads();
    for (int i = tid; i < NBUCK; i += 256) {
        int c = hist[i];
        base[i] = c ? atomicAdd(&bcur[i], c) : 0;
        hist[i] = 0;
    }
    __syncthreads();
#pragma unroll
    for (int i = 0; i < 16; i++) {
        int e = e0 + i * 256 + tid;
        if (e < NEDGES) {
            int d = dstv[e];
            int b = d >> 9;
            int r = atomicAdd(&hist[b], 1);
            packed[base[b] + r] = ((unsigned int)srcv[e] << 9) | (unsigned int)(d & 511);
        }
    }
}

__global__ __launch_bounds__(256) void k_fill2(
    const unsigned int* __restrict__ packed, const int* __restrict__ bcur,
    int2* __restrict__ off2, int* __restrict__ adj) {
    __shared__ int deg[512];
    __shared__ int cur[512];
    int tid = threadIdx.x;
    int b = blockIdx.x;
    int base = b * BUCKCAP;
    int cnt = bcur[b] - base;
    deg[tid] = 0; deg[tid + 256] = 0;
    __syncthreads();
    for (int i = tid; i < cnt; i += 256)
        atomicAdd(&deg[packed[base + i] & 511], 1);
    __syncthreads();
    cur[tid] = deg[tid]; cur[tid + 256] = deg[tid + 256];
    __syncthreads();
    for (int o = 1; o < 512; o <<= 1) {
        int u0 = (tid >= o) ? cur[tid - o] : 0;
        int u1 = (tid + 256 >= o) ? cur[tid + 256 - o] : 0;
        __syncthreads();
        cur[tid] += u0; cur[tid + 256] += u1;
        __syncthreads();
    }
    int nbase = b * 512;
#pragma unroll
    for (int i = 0; i < 2; i++) {
        int t = tid + i * 256;
        int st = base + cur[t] - deg[t];
        int n = nbase + t;
        if (n < NNODES) off2[n] = make_int2(st, st + deg[t]);
    }
    __syncthreads();
#pragma unroll
    for (int i = 0; i < 2; i++) {
        int t = tid + i * 256;
        cur[t] = base + cur[t] - deg[t];
    }
    __syncthreads();
    for (int i = tid; i < cnt; i += 256) {
        unsigned int p = packed[base + i];
        int r = atomicAdd(&cur[p & 511], 1);
        adj[r] = (int)(p >> 9);
    }
}

// ---------------- W transpose to bf16 ----------------
__global__ void k_wt(const float* __restrict__ w1, const float* __restrict__ w2,
                     unsigned short* __restrict__ WT) {
    int t = blockIdx.x * 256 + threadIdx.x;
    int mat = t >> 14;
    int rem = t & 16383;
    int k = rem >> 7, n = rem & 127;
    const float* src = (mat < 5) ? &w1[(size_t)mat * 16384] : &w2[(size_t)(mat - 5) * 16384];
    WT[(size_t)mat * 16384 + n * 128 + k] = f2b(src[k * 128 + n]);
}

// ------- FUSED agg+GEMM1: z=agg(hb) in LDS; tb = bf16(z@W+b); stats ---------
__global__ __launch_bounds__(256) void k_aggemm1(
    const ushort* __restrict__ hb, const int2* __restrict__ off2,
    const int* __restrict__ adj, const unsigned short* __restrict__ WT,
    const float* __restrict__ bias, ushort* __restrict__ C,
    float* __restrict__ stats) {
    __shared__ ushort zs[128 * ZSTR];   // bf16 z-tile, padded rows
    __shared__ float lstat[256];
    int tid = threadIdx.x;
    int nbase = blockIdx.x * 128;
    const ushort4* hb4 = (const ushort4*)hb;

    // ---- stage 1: aggregate 128 rows into LDS (8 nodes per pass) ----
    int d4 = tid & 31;
    int sub = tid >> 5;
    for (int it = 0; it < 16; it++) {
        int lr = it * 8 + sub;
        int node = nbase + lr;
        ushort4 o;
        if (node < NNODES) {
            ushort4 sv = hb4[(size_t)node * 32 + d4];
            float4 v = make_float4(b2f(sv.x), b2f(sv.y), b2f(sv.z), b2f(sv.w));
            int2 oo = off2[node];
            int e = oo.x, e1 = oo.y;
            for (; e + 8 <= e1; e += 8) {
                int s[8]; ushort4 u[8];
#pragma unroll
                for (int j = 0; j < 8; j++) s[j] = adj[e + j];
#pragma unroll
                for (int j = 0; j < 8; j++) u[j] = hb4[(size_t)s[j] * 32 + d4];
#pragma unroll
                for (int j = 0; j < 8; j++) {
                    v.x += b2f(u[j].x); v.y += b2f(u[j].y);
                    v.z += b2f(u[j].z); v.w += b2f(u[j].w);
                }
            }
            for (; e + 4 <= e1; e += 4) {
                int s0 = adj[e], s1 = adj[e + 1], s2 = adj[e + 2], s3 = adj[e + 3];
                ushort4 u0 = hb4[(size_t)s0 * 32 + d4];
                ushort4 u1 = hb4[(size_t)s1 * 32 + d4];
                ushort4 u2 = hb4[(size_t)s2 * 32 + d4];
                ushort4 u3 = hb4[(size_t)s3 * 32 + d4];
                v.x += (b2f(u0.x) + b2f(u1.x)) + (b2f(u2.x) + b2f(u3.x));
                v.y += (b2f(u0.y) + b2f(u1.y)) + (b2f(u2.y) + b2f(u3.y));
                v.z += (b2f(u0.z) + b2f(u1.z)) + (b2f(u2.z) + b2f(u3.z));
                v.w += (b2f(u0.w) + b2f(u1.w)) + (b2f(u2.w) + b2f(u3.w));
            }
            for (; e < e1; e++) {
                int s = adj[e];
                ushort4 u = hb4[(size_t)s * 32 + d4];
                v.x += b2f(u.x); v.y += b2f(u.y); v.z += b2f(u.z); v.w += b2f(u.w);
            }
            o.x = f2b(v.x); o.y = f2b(v.y); o.z = f2b(v.z); o.w = f2b(v.w);
        } else {
            o = make_ushort4(0, 0, 0, 0);
        }
        *(ushort4*)&zs[lr * ZSTR + d4 * 4] = o;
    }
    __syncthreads();

    // ---- stage 2: MFMA from LDS ----
    int wave = tid >> 6;
    int lane = tid & 63;
    int q = lane >> 4;
    int l16 = lane & 15;
    int lrow0 = wave * 32;

    f32x4 acc[2][8];
#pragma unroll
    for (int rt = 0; rt < 2; rt++)
#pragma unroll
        for (int nt = 0; nt < 8; nt++) acc[rt][nt] = (f32x4){0.f, 0.f, 0.f, 0.f};

    for (int kc = 0; kc < 4; kc++) {
        int k0 = kc * 32 + q * 8;
        short8 bf[8];
#pragma unroll
        for (int nt = 0; nt < 8; nt++)
            bf[nt] = *(const short8*)&WT[(size_t)(nt * 16 + l16) * 128 + k0];
#pragma unroll
        for (int rt = 0; rt < 2; rt++) {
            short8 av = *(const short8*)&zs[(lrow0 + rt * 16 + l16) * ZSTR + k0];
#pragma unroll
            for (int nt = 0; nt < 8; nt++)
                acc[rt][nt] = __builtin_amdgcn_mfma_f32_16x16x32_bf16(
                    av, bf[nt], acc[rt][nt], 0, 0, 0);
        }
    }

    lstat[tid] = 0.f;
    __syncthreads();
    int rowbase = nbase + lrow0;
#pragma unroll
    for (int nt = 0; nt < 8; nt++) {
        float b = bias[nt * 16 + l16];
        float csum = 0.f, csq = 0.f;
#pragma unroll
        for (int rt = 0; rt < 2; rt++) {
            int rb = rowbase + rt * 16 + q * 4;
#pragma unroll
            for (int r = 0; r < 4; r++) {
                int row = rb + r;
                if (row < NNODES) {
                    float v = acc[rt][nt][r] + b;
                    C[(size_t)row * 128 + nt * 16 + l16] = f2b(v);
                    csum += v; csq += v * v;
                }
            }
        }
        csum += __shfl_xor(csum, 16, 64); csq += __shfl_xor(csq, 16, 64);
        csum += __shfl_xor(csum, 32, 64); csq += __shfl_xor(csq, 32, 64);
        if (q == 0) {
            atomicAdd(&lstat[nt * 16 + l16], csum);
            atomicAdd(&lstat[128 + nt * 16 + l16], csq);
        }
    }
    __syncthreads();
    atomicAdd(&stats[((blockIdx.x & (NREP - 1)) << 8) + tid], lstat[tid]);
}

// --------- GEMM2: t2b = bf16(relu(BN1(tb)) @ W + bias), stats -> replica ----
__global__ __launch_bounds__(256) void k_gemm2(
    const ushort* __restrict__ A, const unsigned short* __restrict__ WT,
    const float* __restrict__ bias, ushort* __restrict__ C,
    const float* __restrict__ statsIn, const float* __restrict__ gamma,
    const float* __restrict__ beta, float* __restrict__ stats) {
    __shared__ float lstat[256];
    __shared__ float s_sc[128], s_sh[128];
    int tid = threadIdx.x;
    if (tid < 128) {
        float s = 0.f, qq = 0.f;
#pragma unroll
        for (int r = 0; r < NREP; r++) {
            s  += statsIn[r * 256 + tid];
            qq += statsIn[r * 256 + 128 + tid];
        }
        float m = s * (1.f / NNODES);
        float var = qq * (1.f / NNODES) - m * m;
        float sc = gamma[tid] * rsqrtf(var + BN_EPS);
        s_sc[tid] = sc;
        s_sh[tid] = beta[tid] - m * sc;
    }
    __syncthreads();

    int wave = tid >> 6;
    int lane = tid & 63;
    int q = lane >> 4;
    int l16 = lane & 15;
    int rowbase = blockIdx.x * 128 + wave * 32;

    f32x4 acc[2][8];
#pragma unroll
    for (int rt = 0; rt < 2; rt++)
#pragma unroll
        for (int nt = 0; nt < 8; nt++) acc[rt][nt] = (f32x4){0.f, 0.f, 0.f, 0.f};

    for (int kc = 0; kc < 4; kc++) {
        int k0 = kc * 32 + q * 8;
        short8 bf[8];
#pragma unroll
        for (int nt = 0; nt < 8; nt++)
            bf[nt] = *(const short8*)&WT[(size_t)(nt * 16 + l16) * 128 + k0];

        float4 s0 = *(const float4*)&s_sc[k0];
        float4 s1 = *(const float4*)&s_sc[k0 + 4];
        float4 t0 = *(const float4*)&s_sh[k0];
        float4 t1 = *(const float4*)&s_sh[k0 + 4];
        float scl[8] = {s0.x, s0.y, s0.z, s0.w, s1.x, s1.y, s1.z, s1.w};
        float shf[8] = {t0.x, t0.y, t0.z, t0.w, t1.x, t1.y, t1.z, t1.w};
#pragma unroll
        for (int rt = 0; rt < 2; rt++) {
            int row = rowbase + rt * 16 + l16;
            if (row >= NNODES) row = NNODES - 1;
            union { short8 s; unsigned short u[8]; } in, cv;
            in.s = *(const short8*)&A[(size_t)row * 128 + k0];
#pragma unroll
            for (int j = 0; j < 8; j++) {
                float f = fmaxf(b2f(in.u[j]) * scl[j] + shf[j], 0.f);
                cv.u[j] = f2b(f);
            }
#pragma unroll
            for (int nt = 0; nt < 8; nt++)
                acc[rt][nt] = __builtin_amdgcn_mfma_f32_16x16x32_bf16(
                    cv.s, bf[nt], acc[rt][nt], 0, 0, 0);
        }
    }

    lstat[tid] = 0.f;
    __syncthreads();
#pragma unroll
    for (int nt = 0; nt < 8; nt++) {
        float b = bias[nt * 16 + l16];
        float csum = 0.f, csq = 0.f;
#pragma unroll
        for (int rt = 0; rt < 2; rt++) {
            int rb = rowbase + rt * 16 + q * 4;
#pragma unroll
            for (int r = 0; r < 4; r++) {
                int row = rb + r;
                if (row < NNODES) {
                    float v = acc[rt][nt][r] + b;
                    C[(size_t)row * 128 + nt * 16 + l16] = f2b(v);
                    csum += v; csq += v * v;
                }
            }
        }
        csum += __shfl_xor(csum, 16, 64); csq += __shfl_xor(csq, 16, 64);
        csum += __shfl_xor(csum, 32, 64); csq += __shfl_xor(csq, 32, 64);
        if (q == 0) {
            atomicAdd(&lstat[nt * 16 + l16], csum);
            atomicAdd(&lstat[128 + nt * 16 + l16], csq);
        }
    }
    __syncthreads();
    atomicAdd(&stats[((blockIdx.x & (NREP - 1)) << 8) + tid], lstat[tid]);
}

// ---- resid: h += relu(BN2(t2b)); hb = bf16(h) ----
__global__ void k_resid(float* __restrict__ h, ushort* __restrict__ hb,
                        const ushort* __restrict__ t2b,
                        const float* __restrict__ statsIn,
                        const float* __restrict__ gamma, const float* __restrict__ beta) {
    __shared__ float s_sc[128], s_sh[128];
    int tid = threadIdx.x;
    if (tid < 128) {
        float s = 0.f, qq = 0.f;
#pragma unroll
        for (int r = 0; r < NREP; r++) {
            s  += statsIn[r * 256 + tid];
            qq += statsIn[r * 256 + 128 + tid];
        }
        float m = s * (1.f / NNODES);
        float var = qq * (1.f / NNODES) - m * m;
        float sc = gamma[tid] * rsqrtf(var + BN_EPS);
        s_sc[tid] = sc;
        s_sh[tid] = beta[tid] - m * sc;
    }
    __syncthreads();
    int i = blockIdx.x * 256 + tid;
    int c4 = (i & 31) * 4;
    float4 sc = *(const float4*)&s_sc[c4];
    float4 sh = *(const float4*)&s_sh[c4];
    ushort4 t = ((const ushort4*)t2b)[i];
    float4 hv = ((float4*)h)[i];
    hv.x += fmaxf(b2f(t.x) * sc.x + sh.x, 0.f);
    hv.y += fmaxf(b2f(t.y) * sc.y + sh.y, 0.f);
    hv.z += fmaxf(b2f(t.z) * sc.z + sh.z, 0.f);
    hv.w += fmaxf(b2f(t.w) * sc.w + sh.w, 0.f);
    ((float4*)h)[i] = hv;
    ushort4 o;
    o.x = f2b(hv.x); o.y = f2b(hv.y); o.z = f2b(hv.z); o.w = f2b(hv.w);
    ((ushort4*)hb)[i] = o;
}

// ---------------- pooling + projection ----------------
__global__ void k_pool(const float* __restrict__ h, const int* __restrict__ batch,
                       float* __restrict__ pooled) {
    __shared__ float4 red[256];
    int t = threadIdx.x;
    int d4 = t & 31, sub = t >> 5;
    int n0 = blockIdx.x * 128;
    if (n0 >= NNODES) return;
    int n1 = n0 + 128; if (n1 > NNODES) n1 = NNODES;
    int glo = batch[n0], ghi = batch[n1 - 1];
    for (int g = glo; g <= ghi; g++) {
        float4 acc = make_float4(0.f, 0.f, 0.f, 0.f);
        for (int r = n0 + sub; r < n1; r += 8) {
            if (batch[r] == g) {
                float4 v = ((const float4*)h)[(size_t)r * 32 + d4];
                acc.x += v.x; acc.y += v.y; acc.z += v.z; acc.w += v.w;
            }
        }
        red[t] = acc;
        __syncthreads();
        if (sub < 4) {
            float4 o = red[t + 128];
            red[t].x += o.x; red[t].y += o.y; red[t].z += o.z; red[t].w += o.w;
        }
        __syncthreads();
        if (sub < 2) {
            float4 o = red[t + 64];
            red[t].x += o.x; red[t].y += o.y; red[t].z += o.z; red[t].w += o.w;
        }
        __syncthreads();
        if (sub == 0) {
            float4 o = red[t + 32];
            float4 a = red[t];
            a.x += o.x; a.y += o.y; a.z += o.z; a.w += o.w;
            atomicAdd(&pooled[g * 128 + d4 * 4 + 0], a.x);
            atomicAdd(&pooled[g * 128 + d4 * 4 + 1], a.y);
            atomicAdd(&pooled[g * 128 + d4 * 4 + 2], a.z);
            atomicAdd(&pooled[g * 128 + d4 * 4 + 3], a.w);
        }
        __syncthreads();
    }
}

// projection; graph count computed in-kernel (binary search by thread 0)
__global__ void k_proj(const float* __restrict__ pooled, const int* __restrict__ batch,
                       const float* __restrict__ wp, const float* __restrict__ bp,
                       float* __restrict__ out) {
    __shared__ float prow[128];
    __shared__ float inv_cnt;
    int g = blockIdx.x, c = threadIdx.x;
    if (c == 0) {
        auto lb = [&](int key) {
            int lo = 0, hi = NNODES;
            while (lo < hi) {
                int mid = (lo + hi) >> 1;
                if (batch[mid] < key) lo = mid + 1; else hi = mid;
            }
            return lo;
        };
        float cnt = (float)(lb(g + 1) - lb(g));
        inv_cnt = 1.f / fmaxf(cnt, 1.f);
    }
    __syncthreads();
    if (c < 128) prow[c] = pooled[g * 128 + c] * inv_cnt;
    __syncthreads();
    float acc = bp[c];
    for (int k = 0; k < 128; k++) acc += prow[k] * wp[k * 256 + c];
    out[g * 256 + c] = acc;
}

extern "C" void kernel_launch(void* const* d_in, const int* in_sizes, int n_in,
                              void* d_out, int out_size, void* d_ws, size_t ws_size,
                              hipStream_t stream) {
    const float* x    = (const float*)d_in[0];
    const int*   eidx = (const int*)d_in[1];
    const int*   batch= (const int*)d_in[2];
    const float* w1   = (const float*)d_in[3];
    const float* b1   = (const float*)d_in[4];
    const float* g1   = (const float*)d_in[5];
    const float* be1  = (const float*)d_in[6];
    const float* w2   = (const float*)d_in[7];
    const float* b2   = (const float*)d_in[8];
    const float* gbn  = (const float*)d_in[9];
    const float* bbn  = (const float*)d_in[10];
    const float* wp   = (const float*)d_in[11];
    const float* bp   = (const float*)d_in[12];

    float* out  = (float*)d_out;
    float* gemb = out;                          // [64,256]
    float* h    = out + (size_t)NGRAPHS * OUTD; // node_emb lives in d_out

    char* w = (char*)d_ws;
    ushort* hb   = (ushort*)w; w += (size_t)NNODES * 128 * 2; // bf16 mirror of h
    ushort* tb   = (ushort*)w; w += (size_t)NNODES * 128 * 2; // bf16 t
    ushort* t2b  = (ushort*)w; w += (size_t)NNODES * 128 * 2; // bf16 t2
    int2*  off2  = (int2*)w;  w += (size_t)NNODES * 8;
    int*   adj   = (int*)w;   w += (size_t)NBUCK * BUCKCAP * 4;
    unsigned short* WT = (unsigned short*)w; w += (size_t)10 * 16384 * 2;
    int*   bcur  = (int*)w;   w += 256 * 4;
    float* statsAll = (float*)w; w += (size_t)10 * NREP * 256 * 4;
    float* pooled= (float*)w; w += (size_t)NGRAPHS * HID * 4;

    // packed edge buffer aliases tb (dead until layer loop)
    unsigned int* packed = (unsigned int*)tb;

    const int* srcv = eidx;
    const int* dstv = eidx + NEDGES;

    // h = x, hb = bf16(x)
    k_init<<<NNODES * 32 / 256, 256, 0, stream>>>(x, h, hb);

    // W transposes (bf16), once
    k_wt<<<640, 256, 0, stream>>>(w1, w2, WT);

    // zero stats replicas + pooled in one shot (contiguous)
    hipMemsetAsync(statsAll, 0,
                   ((size_t)10 * NREP * 256 + NGRAPHS * HID) * 4, stream);

    // CSR build: bucket scatter -> bucket-local hist/scan/fill
    k_bcur0<<<1, 256, 0, stream>>>(bcur);
    k_fill1<<<FILL_BLOCKS, 256, 0, stream>>>(srcv, dstv, bcur, packed);
    k_fill2<<<NBUCK, 256, 0, stream>>>(packed, bcur, off2, adj);

    const int GB = (NNODES + 127) / 128;  // 782
    for (int i = 0; i < NLAYERS; i++) {
        float* st1 = statsAll + (size_t)(2 * i) * NREP * 256;
        float* st2 = statsAll + (size_t)(2 * i + 1) * NREP * 256;
        k_aggemm1<<<GB, 256, 0, stream>>>(
            hb, off2, adj, WT + (size_t)i * 16384, b1 + i * HID, tb, st1);
        k_gemm2<<<GB, 256, 0, stream>>>(
            tb, WT + (size_t)(5 + i) * 16384, b2 + i * HID, t2b,
            st1, g1 + i * HID, be1 + i * HID, st2);
        k_resid<<<NNODES * 128 / 4 / 256, 256, 0, stream>>>(
            h, hb, t2b, st2, gbn + i * HID, bbn + i * HID);
    }

    // pooling + projection
    k_pool<<<(NNODES + 127) / 128, 256, 0, stream>>>(h, batch, pooled);
    k_proj<<<NGRAPHS, 256, 0, stream>>>(pooled, batch, wp, bp, gemb);
}